// Round 7
// baseline (926.126 us; speedup 1.0000x reference)
//
#include <hip/hip_runtime.h>

#define NN 100000
#define EE 1600000
#define HH 128
#define GG 64
#define TOT (EE + NN)
#define PSPLIT 8
#define NB 782            // (NN+127)/128 buckets of 128 dst nodes
#define BCAP 4096         // max edges per bucket held in LDS (mean 2048, std ~45)

typedef __attribute__((ext_vector_type(8))) short s16x8;
typedef __attribute__((ext_vector_type(4))) float f32x4;

__device__ __forceinline__ unsigned short f2bf(float f) {
    unsigned u = __float_as_uint(f);
    u = u + 0x7FFFu + ((u >> 16) & 1u);   // round-to-nearest-even
    return (unsigned short)(u >> 16);
}

// ---------------- graph prep ----------------

__global__ void init_kernel(int* bucketCnt, int* gstart, int* gend, float* poolsum) {
    int i = blockIdx.x * blockDim.x + threadIdx.x;
    if (i < NB) bucketCnt[i] = 0;
    if (i < GG) { gstart[i] = NN; gend[i] = 0; }
    if (i < GG * HH) poolsum[i] = 0.f;
}

// per-block LDS histogram of dst buckets, grid-stride
__global__ __launch_bounds__(256) void hist_kernel(const int* __restrict__ ei, int* bucketCnt) {
    __shared__ int h[NB];
    int tid = threadIdx.x;
    for (int i = tid; i < NB; i += 256) h[i] = 0;
    __syncthreads();
    for (int e = blockIdx.x * 256 + tid; e < EE; e += gridDim.x * 256) {
        unsigned c = (unsigned)ei[EE + e];
        if (c < NN) atomicAdd(&h[c >> 7], 1);
    }
    __syncthreads();
    for (int i = tid; i < NB; i += 256) {
        int v = h[i];
        if (v) atomicAdd(&bucketCnt[i], v);
    }
}

// single-block scan over buckets: edge offsets + slot offsets (slots = edges + self-loops)
__global__ void bscan_kernel(const int* __restrict__ bucketCnt, int* __restrict__ bucketEdgeStart,
                             int* __restrict__ bucketSlotStart, int* __restrict__ cursor,
                             int* __restrict__ col_start) {
    __shared__ int se[1024], ss[1024];
    int t = threadIdx.x;
    int ec = (t < NB) ? bucketCnt[t] : 0;
    int nc = (t < NB) ? min(128, NN - t * 128) : 0;
    se[t] = ec; ss[t] = ec + nc;
    __syncthreads();
    for (int off = 1; off < 1024; off <<= 1) {
        int a = 0, b = 0;
        if (t >= off) { a = se[t - off]; b = ss[t - off]; }
        __syncthreads();
        se[t] += a; ss[t] += b;
        __syncthreads();
    }
    if (t < NB) {
        bucketEdgeStart[t] = se[t] - ec;
        bucketSlotStart[t] = ss[t] - (ec + nc);
        cursor[t] = se[t] - ec;
    }
    if (t == NB - 1) col_start[NN] = ss[t];   // total slots
}

// scatter packed (src<<7 | dstLocal) into bucket-contiguous regions: dense write lines
__global__ void bfill_kernel(const int* __restrict__ ei, int* cursor, unsigned* __restrict__ ebuf) {
    int e = blockIdx.x * blockDim.x + threadIdx.x;
    if (e >= EE) return;
    unsigned r = (unsigned)ei[e];
    unsigned c = (unsigned)ei[EE + e];
    if (r >= NN || c >= NN) return;
    int slot = atomicAdd(&cursor[c >> 7], 1);
    if (slot >= 0 && slot < EE) ebuf[slot] = (r << 7) | (c & 127u);
}

// one block per bucket: local count/scan in LDS, emit col_start/dinv/srcv sequentially
__global__ __launch_bounds__(256) void bproc_kernel(const unsigned* __restrict__ ebuf,
                                                    const int* __restrict__ bucketCnt,
                                                    const int* __restrict__ bucketEdgeStart,
                                                    const int* __restrict__ bucketSlotStart,
                                                    int* __restrict__ col_start,
                                                    float* __restrict__ dinv,
                                                    int* __restrict__ srcv) {
    __shared__ unsigned s_e[BCAP];
    __shared__ int s_cnt[128], s_scan[128], s_cur[128];
    int b = blockIdx.x;
    int tid = threadIdx.x;
    int n0 = b * 128;
    int nb = min(128, NN - n0);
    int est = bucketEdgeStart[b];
    int ecnt = min(bucketCnt[b], BCAP);
    if (tid < 128) s_cnt[tid] = 0;
    __syncthreads();
    for (int i = tid; i < ecnt; i += 256) {
        unsigned v = ebuf[est + i];
        s_e[i] = v;
        atomicAdd(&s_cnt[v & 127u], 1);
    }
    __syncthreads();
    int myc = 0;
    if (tid < 128) {
        myc = (tid < nb) ? s_cnt[tid] + 1 : 0;   // +1 self-loop
        s_scan[tid] = myc;
    }
    __syncthreads();
    for (int off = 1; off < 128; off <<= 1) {
        int a = 0;
        if (tid < 128 && tid >= off) a = s_scan[tid - off];
        __syncthreads();
        if (tid < 128) s_scan[tid] += a;
        __syncthreads();
    }
    if (tid < nb) {
        int slotbase = bucketSlotStart[b] + s_scan[tid] - myc;
        col_start[n0 + tid] = slotbase;
        dinv[n0 + tid] = rsqrtf((float)(s_cnt[tid] + 1));
        srcv[slotbase] = n0 + tid;               // self-loop first
        s_cur[tid] = slotbase + 1;
    }
    __syncthreads();
    for (int i = tid; i < ecnt; i += 256) {
        unsigned v = s_e[i];
        int slot = atomicAdd(&s_cur[v & 127u], 1);
        srcv[slot] = (int)(v >> 7);
    }
}

// batch is sorted -> group bounds are run boundaries; plain stores, no atomics.
__global__ void bounds_kernel(const int* __restrict__ batch, int* gstart, int* gend) {
    int i = blockIdx.x * blockDim.x + threadIdx.x;
    if (i >= NN) return;
    int b = batch[i];
    if (i == 0) {
        gstart[b] = 0;
    } else {
        int bp = batch[i - 1];
        if (b != bp) {
            gstart[b] = i;
            gend[bp] = i;
        }
    }
    if (i == NN - 1) gend[b] = NN;
}

// cast+transpose all 3 W (fp32 [k][n]) -> Wt bf16 [n][k], one launch
__global__ void wprep_kernel(const float* __restrict__ W0, const float* __restrict__ W1,
                             const float* __restrict__ W2, unsigned short* __restrict__ Wt) {
    int i = blockIdx.x * 256 + threadIdx.x;
    int l = i >> 14;                      // HH*HH = 16384 per layer
    int r = i & 16383;
    if (l < 3) {
        const float* W = (l == 0) ? W0 : (l == 1) ? W1 : W2;
        int k = r >> 7, n = r & 127;
        Wt[l * HH * HH + n * HH + k] = f2bf(W[r]);
    }
}

// cast x fp32 -> Xbf (packed 2 bf16 per uint; low = even col)
__global__ void cast_kernel(const float* __restrict__ x, unsigned* __restrict__ Xbf) {
    int i = blockIdx.x * blockDim.x + threadIdx.x;   // uint index
    if (i >= NN * 64) return;
    float2 v = ((const float2*)x)[i];
    Xbf[i] = (unsigned)f2bf(v.x) | ((unsigned)f2bf(v.y) << 16);
}

// ---------------- per-layer kernels ----------------

// one wave per dst node; uint4 gathers (16B/lane, 4 rows/issue, 4-pair unroll = 16 rows
// in flight); cross-quarter shfl reduce; bf16 out. Block 0 zeroes BN stats.
__global__ __launch_bounds__(256) void agg_kernel(const uint4* __restrict__ Xbf4,
                                                  const int* __restrict__ col_start,
                                                  const int* __restrict__ srcv,
                                                  const float* __restrict__ dinv,
                                                  unsigned short* __restrict__ Abf,
                                                  float* __restrict__ gsum,
                                                  float* __restrict__ gsq) {
    if (blockIdx.x == 0 && threadIdx.x < HH) {
        gsum[threadIdx.x] = 0.f;
        gsq[threadIdx.x] = 0.f;
    }
    int wid = (int)((blockIdx.x * blockDim.x + threadIdx.x) >> 6);
    int lane = threadIdx.x & 63;
    if (wid >= NN) return;
    int s0 = col_start[wid], s1 = col_start[wid + 1];
    float dd = dinv[wid];
    int q = lane >> 4;        // quarter: which neighbor of the group of 4
    int l16 = lane & 15;      // 16 lanes cover one 256B row (uint4 each)
    float acc[8];
#pragma unroll
    for (int j = 0; j < 8; ++j) acc[j] = 0.f;

    for (int base = s0; base < s1; base += 64) {
        int cnt = min(64, s1 - base);
        int msrc = 0;
        float mw = 0.f;
        if (lane < cnt) { msrc = srcv[base + lane]; mw = dinv[msrc] * dd; }
        int rounds = (cnt + 3) >> 2;
        int p = 0;
        for (; p + 4 <= rounds; p += 4) {
            uint4 u[4];
            float w[4];
#pragma unroll
            for (int k = 0; k < 4; ++k) {
                int idx = (p + k) * 4 + q;
                int src = __shfl(msrc, idx);
                w[k] = __shfl(mw, idx);           // 0 beyond cnt
                u[k] = Xbf4[(size_t)src * 16 + l16];
            }
#pragma unroll
            for (int k = 0; k < 4; ++k) {
                acc[0] += w[k] * __uint_as_float(u[k].x << 16);
                acc[1] += w[k] * __uint_as_float(u[k].x & 0xFFFF0000u);
                acc[2] += w[k] * __uint_as_float(u[k].y << 16);
                acc[3] += w[k] * __uint_as_float(u[k].y & 0xFFFF0000u);
                acc[4] += w[k] * __uint_as_float(u[k].z << 16);
                acc[5] += w[k] * __uint_as_float(u[k].z & 0xFFFF0000u);
                acc[6] += w[k] * __uint_as_float(u[k].w << 16);
                acc[7] += w[k] * __uint_as_float(u[k].w & 0xFFFF0000u);
            }
        }
        for (; p < rounds; ++p) {
            int idx = p * 4 + q;
            int src = __shfl(msrc, idx);
            float w = __shfl(mw, idx);
            uint4 u = Xbf4[(size_t)src * 16 + l16];
            acc[0] += w * __uint_as_float(u.x << 16);
            acc[1] += w * __uint_as_float(u.x & 0xFFFF0000u);
            acc[2] += w * __uint_as_float(u.y << 16);
            acc[3] += w * __uint_as_float(u.y & 0xFFFF0000u);
            acc[4] += w * __uint_as_float(u.z << 16);
            acc[5] += w * __uint_as_float(u.z & 0xFFFF0000u);
            acc[6] += w * __uint_as_float(u.w << 16);
            acc[7] += w * __uint_as_float(u.w & 0xFFFF0000u);
        }
    }
#pragma unroll
    for (int j = 0; j < 8; ++j) {
        acc[j] += __shfl_xor(acc[j], 16);
        acc[j] += __shfl_xor(acc[j], 32);
    }
    if (q == 0) {
        uint4 pk;
        pk.x = (unsigned)f2bf(acc[0]) | ((unsigned)f2bf(acc[1]) << 16);
        pk.y = (unsigned)f2bf(acc[2]) | ((unsigned)f2bf(acc[3]) << 16);
        pk.z = (unsigned)f2bf(acc[4]) | ((unsigned)f2bf(acc[5]) << 16);
        pk.w = (unsigned)f2bf(acc[6]) | ((unsigned)f2bf(acc[7]) << 16);
        ((uint4*)Abf)[(size_t)wid * 16 + l16] = pk;
    }
}

// pass 1: MFMA product, BN column sum/sumsq only — H never materialized.
__global__ __launch_bounds__(256) void gemm_stats_kernel(const unsigned short* __restrict__ Abf,
                                                         const unsigned short* __restrict__ Wt,
                                                         const float* __restrict__ bias,
                                                         float* __restrict__ gsum,
                                                         float* __restrict__ gsq) {
    __shared__ unsigned short wlds[128 * 136];   // row stride 136 bf16 = 272B: no b128 conflicts
    __shared__ float ssum[HH], ssq[HH];
    int tid = threadIdx.x;
    if (tid < HH) { ssum[tid] = 0.f; ssq[tid] = 0.f; }
#pragma unroll
    for (int it = 0; it < 16; ++it) {
        int idx = it * 256 + tid;
        int r = idx >> 5, c = idx & 31;
        *(uint2*)&wlds[r * 136 + c * 4] = *(const uint2*)(Wt + r * HH + c * 4);
    }
    __syncthreads();

    int lane = tid & 63;
    int wave = tid >> 6;
    int mcol = lane & 15;
    int quad = lane >> 4;
    int rowbase = blockIdx.x * 128 + wave * 32;
    int row0 = rowbase + mcol;
    int row1 = row0 + 16;

    f32x4 acc[2][8];
#pragma unroll
    for (int mt = 0; mt < 2; ++mt)
#pragma unroll
        for (int nt = 0; nt < 8; ++nt) acc[mt][nt] = (f32x4){0.f, 0.f, 0.f, 0.f};

    s16x8 zf = {0, 0, 0, 0, 0, 0, 0, 0};
#pragma unroll
    for (int ks = 0; ks < 4; ++ks) {
        int k0 = ks * 32 + quad * 8;
        s16x8 a0 = (row0 < NN) ? *(const s16x8*)(Abf + (size_t)row0 * HH + k0) : zf;
        s16x8 a1 = (row1 < NN) ? *(const s16x8*)(Abf + (size_t)row1 * HH + k0) : zf;
#pragma unroll
        for (int nt = 0; nt < 8; ++nt) {
            s16x8 b = *(const s16x8*)&wlds[(nt * 16 + mcol) * 136 + k0];
            acc[0][nt] = __builtin_amdgcn_mfma_f32_16x16x32_bf16(a0, b, acc[0][nt], 0, 0, 0);
            acc[1][nt] = __builtin_amdgcn_mfma_f32_16x16x32_bf16(a1, b, acc[1][nt], 0, 0, 0);
        }
    }

    float s[8], sq[8];
#pragma unroll
    for (int nt = 0; nt < 8; ++nt) { s[nt] = 0.f; sq[nt] = 0.f; }
#pragma unroll
    for (int mt = 0; mt < 2; ++mt) {
        int rbase = rowbase + mt * 16 + quad * 4;
#pragma unroll
        for (int nt = 0; nt < 8; ++nt) {
            float bv = bias[nt * 16 + mcol];
            f32x4 a = acc[mt][nt];
#pragma unroll
            for (int reg = 0; reg < 4; ++reg) {
                if (rbase + reg < NN) {
                    float h = a[reg] + bv;
                    s[nt] += h; sq[nt] += h * h;
                }
            }
        }
    }
#pragma unroll
    for (int nt = 0; nt < 8; ++nt) {
        float v = s[nt];  v += __shfl_xor(v, 16);  v += __shfl_xor(v, 32);
        float w = sq[nt]; w += __shfl_xor(w, 16);  w += __shfl_xor(w, 32);
        if (quad == 0) {
            atomicAdd(&ssum[nt * 16 + mcol], v);
            atomicAdd(&ssq[nt * 16 + mcol], w);
        }
    }
    __syncthreads();
    if (tid < HH) {
        atomicAdd(&gsum[tid], ssum[tid]);
        atomicAdd(&gsq[tid], ssq[tid]);
    }
}

// pass 2: recompute the identical MFMA product, apply bias+BN+ReLU, store bf16 X.
__global__ __launch_bounds__(256) void gemm_apply_kernel(const unsigned short* __restrict__ Abf,
                                                         const unsigned short* __restrict__ Wt,
                                                         const float* __restrict__ bias,
                                                         const float* __restrict__ gsum,
                                                         const float* __restrict__ gsq,
                                                         const float* __restrict__ g,
                                                         const float* __restrict__ beta,
                                                         unsigned short* __restrict__ Xb16) {
    __shared__ unsigned short wlds[128 * 136];
    __shared__ float asc[HH], bsh[HH];
    int tid = threadIdx.x;
#pragma unroll
    for (int it = 0; it < 16; ++it) {
        int idx = it * 256 + tid;
        int r = idx >> 5, c = idx & 31;
        *(uint2*)&wlds[r * 136 + c * 4] = *(const uint2*)(Wt + r * HH + c * 4);
    }
    if (tid < HH) {
        float mu = gsum[tid] * (1.f / (float)NN);
        float var = fmaxf(gsq[tid] * (1.f / (float)NN) - mu * mu, 0.f);
        float a = g[tid] * rsqrtf(var + 1e-5f);
        asc[tid] = a;
        bsh[tid] = a * (bias[tid] - mu) + beta[tid];   // o = a*acc + bsh
    }
    __syncthreads();

    int lane = tid & 63;
    int wave = tid >> 6;
    int mcol = lane & 15;
    int quad = lane >> 4;
    int rowbase = blockIdx.x * 128 + wave * 32;
    int row0 = rowbase + mcol;
    int row1 = row0 + 16;

    f32x4 acc[2][8];
#pragma unroll
    for (int mt = 0; mt < 2; ++mt)
#pragma unroll
        for (int nt = 0; nt < 8; ++nt) acc[mt][nt] = (f32x4){0.f, 0.f, 0.f, 0.f};

    s16x8 zf = {0, 0, 0, 0, 0, 0, 0, 0};
#pragma unroll
    for (int ks = 0; ks < 4; ++ks) {
        int k0 = ks * 32 + quad * 8;
        s16x8 a0 = (row0 < NN) ? *(const s16x8*)(Abf + (size_t)row0 * HH + k0) : zf;
        s16x8 a1 = (row1 < NN) ? *(const s16x8*)(Abf + (size_t)row1 * HH + k0) : zf;
#pragma unroll
        for (int nt = 0; nt < 8; ++nt) {
            s16x8 b = *(const s16x8*)&wlds[(nt * 16 + mcol) * 136 + k0];
            acc[0][nt] = __builtin_amdgcn_mfma_f32_16x16x32_bf16(a0, b, acc[0][nt], 0, 0, 0);
            acc[1][nt] = __builtin_amdgcn_mfma_f32_16x16x32_bf16(a1, b, acc[1][nt], 0, 0, 0);
        }
    }

#pragma unroll
    for (int mt = 0; mt < 2; ++mt) {
        int rbase = rowbase + mt * 16 + quad * 4;
#pragma unroll
        for (int nt = 0; nt < 8; ++nt) {
            int col = nt * 16 + mcol;
            float av = asc[col], bv = bsh[col];
            f32x4 a = acc[mt][nt];
#pragma unroll
            for (int reg = 0; reg < 4; ++reg) {
                int r = rbase + reg;
                if (r < NN) {
                    float o = fmaxf(av * a[reg] + bv, 0.f);
                    Xb16[(size_t)r * HH + col] = f2bf(o);
                }
            }
        }
    }
}

// ---------------- pooling + fc ----------------

__global__ void pool_kernel(const unsigned* __restrict__ Xbf, const int* __restrict__ gstart,
                            const int* __restrict__ gend, float* __restrict__ poolsum) {
    int g = blockIdx.x;
    int sp = blockIdx.y;
    int t = threadIdx.x;           // 64: each handles 2 cols
    int s = gstart[g], e = gend[g];
    if (e <= s) return;
    int len = e - s;
    int chunk = (len + PSPLIT - 1) / PSPLIT;
    int cs = s + sp * chunk;
    int ce = min(cs + chunk, e);
    if (cs >= ce) return;
    float2 acc = make_float2(0.f, 0.f);
    for (int i = cs; i < ce; ++i) {
        unsigned u = Xbf[(size_t)i * 64 + t];
        acc.x += __uint_as_float(u << 16);
        acc.y += __uint_as_float(u & 0xFFFF0000u);
    }
    atomicAdd(&poolsum[g * HH + 2 * t], acc.x);
    atomicAdd(&poolsum[g * HH + 2 * t + 1], acc.y);
}

__global__ void fc_kernel(const float* __restrict__ poolsum, const int* __restrict__ gstart,
                          const int* __restrict__ gend, const float* __restrict__ fc_w,
                          const float* __restrict__ fc_b, float* __restrict__ out) {
    int g = blockIdx.x;
    int o = threadIdx.x;
    int cnt = gend[g] - gstart[g];
    float inv = (cnt > 0) ? (1.f / (float)cnt) : 0.f;
    float acc = fc_b[o];
    for (int k = 0; k < HH; ++k) acc += (poolsum[g * HH + k] * inv) * fc_w[k * HH + o];
    out[g * HH + o] = acc;
}

// ---------------- launch ----------------

extern "C" void kernel_launch(void* const* d_in, const int* in_sizes, int n_in,
                              void* d_out, int out_size, void* d_ws, size_t ws_size,
                              hipStream_t stream) {
    const float* x     = (const float*)d_in[0];
    const int*   ei    = (const int*)d_in[1];
    const int*   batch = (const int*)d_in[2];
    const float* Wl[3]    = {(const float*)d_in[3], (const float*)d_in[7], (const float*)d_in[11]};
    const float* bl[3]    = {(const float*)d_in[4], (const float*)d_in[8], (const float*)d_in[12]};
    const float* gl[3]    = {(const float*)d_in[5], (const float*)d_in[9], (const float*)d_in[13]};
    const float* betal[3] = {(const float*)d_in[6], (const float*)d_in[10], (const float*)d_in[14]};
    const float* fc_w = (const float*)d_in[15];
    const float* fc_b = (const float*)d_in[16];
    float* out = (float*)d_out;

    char* ws = (char*)d_ws;
    size_t off = 0;
    auto take = [&](size_t n) -> void* {
        void* p = ws + off;
        off = (off + n + 255) & ~(size_t)255;
        return p;
    };
    int*   bucketCnt       = (int*)take((size_t)NB * 4);
    int*   bucketEdgeStart = (int*)take((size_t)NB * 4);
    int*   bucketSlotStart = (int*)take((size_t)NB * 4);
    int*   cursor          = (int*)take((size_t)NB * 4);
    unsigned* ebuf         = (unsigned*)take((size_t)EE * 4);
    int*   col_start       = (int*)take((size_t)(NN + 1) * 4);
    float* dinv            = (float*)take((size_t)NN * 4);
    int*   srcv            = (int*)take((size_t)TOT * 4);
    float* gsum            = (float*)take(HH * 4);
    float* gsq             = (float*)take(HH * 4);
    int*   gstart          = (int*)take(GG * 4);
    int*   gend            = (int*)take(GG * 4);
    float* poolsum         = (float*)take((size_t)GG * HH * 4);
    unsigned short* wt     = (unsigned short*)take((size_t)3 * HH * HH * 2);
    unsigned* Xbf          = (unsigned*)take((size_t)NN * 64 * 4);
    unsigned short* Abf    = (unsigned short*)take((size_t)NN * HH * 2);

    init_kernel<<<(NN + 255) / 256, 256, 0, stream>>>(bucketCnt, gstart, gend, poolsum);
    hist_kernel<<<512, 256, 0, stream>>>(ei, bucketCnt);
    bscan_kernel<<<1, 1024, 0, stream>>>(bucketCnt, bucketEdgeStart, bucketSlotStart, cursor, col_start);
    bfill_kernel<<<(EE + 255) / 256, 256, 0, stream>>>(ei, cursor, ebuf);
    bproc_kernel<<<NB, 256, 0, stream>>>(ebuf, bucketCnt, bucketEdgeStart, bucketSlotStart,
                                         col_start, dinv, srcv);
    bounds_kernel<<<(NN + 255) / 256, 256, 0, stream>>>(batch, gstart, gend);
    wprep_kernel<<<(3 * HH * HH + 255) / 256, 256, 0, stream>>>(Wl[0], Wl[1], Wl[2], wt);
    cast_kernel<<<(NN * 64 + 255) / 256, 256, 0, stream>>>(x, Xbf);

    for (int l = 0; l < 3; ++l) {
        const unsigned short* W = wt + (size_t)l * HH * HH;
        agg_kernel<<<(NN * 64 + 255) / 256, 256, 0, stream>>>((const uint4*)Xbf, col_start, srcv,
                                                              dinv, Abf, gsum, gsq);
        gemm_stats_kernel<<<(NN + 127) / 128, 256, 0, stream>>>(Abf, W, bl[l], gsum, gsq);
        gemm_apply_kernel<<<(NN + 127) / 128, 256, 0, stream>>>(Abf, W, bl[l], gsum, gsq,
                                                                gl[l], betal[l],
                                                                (unsigned short*)Xbf);
    }

    pool_kernel<<<dim3(GG, PSPLIT), 64, 0, stream>>>(Xbf, gstart, gend, poolsum);
    fc_kernel<<<GG, 128, 0, stream>>>(poolsum, gstart, gend, fc_w, fc_b, out);
}

// Round 8
// 571.691 us; speedup vs baseline: 1.6200x; 1.6200x over previous
//
#include <hip/hip_runtime.h>

#define NN 100000
#define EE 1600000
#define HH 128
#define GG 64
#define TOT (EE + NN)
#define PSPLIT 8
#define NB 782            // (NN+127)/128 buckets of 128 dst nodes
#define BCAP 4096         // max edges per bucket held in LDS (mean 2048, std ~45)
#define FCHUNK 4096       // edges per bfill2 block

typedef __attribute__((ext_vector_type(8))) short s16x8;
typedef __attribute__((ext_vector_type(4))) float f32x4;

__device__ __forceinline__ unsigned short f2bf(float f) {
    unsigned u = __float_as_uint(f);
    u = u + 0x7FFFu + ((u >> 16) & 1u);   // round-to-nearest-even
    return (unsigned short)(u >> 16);
}

// ---------------- graph prep ----------------

__global__ void init_kernel(int* bucketCnt, int* gstart, int* gend, float* poolsum) {
    int i = blockIdx.x * blockDim.x + threadIdx.x;
    if (i < NB) bucketCnt[i] = 0;
    if (i < GG) { gstart[i] = NN; gend[i] = 0; }
    if (i < GG * HH) poolsum[i] = 0.f;
}

// per-block LDS histogram of dst buckets, grid-stride
__global__ __launch_bounds__(256) void hist_kernel(const int* __restrict__ ei, int* bucketCnt) {
    __shared__ int h[NB];
    int tid = threadIdx.x;
    for (int i = tid; i < NB; i += 256) h[i] = 0;
    __syncthreads();
    for (int e = blockIdx.x * 256 + tid; e < EE; e += gridDim.x * 256) {
        unsigned c = (unsigned)ei[EE + e];
        if (c < NN) atomicAdd(&h[c >> 7], 1);
    }
    __syncthreads();
    for (int i = tid; i < NB; i += 256) {
        int v = h[i];
        if (v) atomicAdd(&bucketCnt[i], v);
    }
}

// single-block scan over buckets: edge offsets + slot offsets (slots = edges + self-loops)
__global__ void bscan_kernel(const int* __restrict__ bucketCnt, int* __restrict__ bucketEdgeStart,
                             int* __restrict__ bucketSlotStart, int* __restrict__ cursor,
                             int* __restrict__ col_start) {
    __shared__ int se[1024], ss[1024];
    int t = threadIdx.x;
    int ec = (t < NB) ? bucketCnt[t] : 0;
    int nc = (t < NB) ? min(128, NN - t * 128) : 0;
    se[t] = ec; ss[t] = ec + nc;
    __syncthreads();
    for (int off = 1; off < 1024; off <<= 1) {
        int a = 0, b = 0;
        if (t >= off) { a = se[t - off]; b = ss[t - off]; }
        __syncthreads();
        se[t] += a; ss[t] += b;
        __syncthreads();
    }
    if (t < NB) {
        bucketEdgeStart[t] = se[t] - ec;
        bucketSlotStart[t] = ss[t] - (ec + nc);
        cursor[t] = se[t] - ec;
    }
    if (t == NB - 1) col_start[NN] = ss[t];   // total slots
}

// LDS-aggregated bucket scatter: one global atomic per (block, nonempty bucket),
// per-edge RMW moves to LDS; block-local slots are contiguous -> dense write lines.
__global__ __launch_bounds__(256) void bfill2_kernel(const int* __restrict__ ei, int* cursor,
                                                     unsigned* __restrict__ ebuf) {
    __shared__ int h[NB];       // phase1: local count; phase3: local cursor
    __shared__ int lbase[NB];   // reserved global base per bucket
    int tid = threadIdx.x;
    size_t e0 = (size_t)blockIdx.x * FCHUNK;
    for (int i = tid; i < NB; i += 256) h[i] = 0;
    __syncthreads();
    unsigned r[16], c[16];
#pragma unroll
    for (int k = 0; k < 16; ++k) {
        size_t e = e0 + (size_t)k * 256 + tid;
        unsigned rr = 0xFFFFFFFFu, cc = 0;
        if (e < EE) {
            rr = (unsigned)ei[e];
            cc = (unsigned)ei[EE + e];
            if (rr >= NN || cc >= NN) rr = 0xFFFFFFFFu;
        }
        r[k] = rr; c[k] = cc;
        if (rr != 0xFFFFFFFFu) atomicAdd(&h[cc >> 7], 1);
    }
    __syncthreads();
    for (int i = tid; i < NB; i += 256) {
        int cnt = h[i];
        lbase[i] = cnt ? atomicAdd(&cursor[i], cnt) : 0;
    }
    __syncthreads();
    for (int i = tid; i < NB; i += 256) h[i] = 0;
    __syncthreads();
#pragma unroll
    for (int k = 0; k < 16; ++k) {
        if (r[k] != 0xFFFFFFFFu) {
            unsigned cc = c[k];
            int b = cc >> 7;
            int slot = lbase[b] + atomicAdd(&h[b], 1);
            if (slot >= 0 && slot < EE) ebuf[slot] = (r[k] << 7) | (cc & 127u);
        }
    }
}

// one block per bucket: local count/scan in LDS, emit col_start/dinv/srcv sequentially
__global__ __launch_bounds__(256) void bproc_kernel(const unsigned* __restrict__ ebuf,
                                                    const int* __restrict__ bucketCnt,
                                                    const int* __restrict__ bucketEdgeStart,
                                                    const int* __restrict__ bucketSlotStart,
                                                    int* __restrict__ col_start,
                                                    float* __restrict__ dinv,
                                                    int* __restrict__ srcv) {
    __shared__ unsigned s_e[BCAP];
    __shared__ int s_cnt[128], s_scan[128], s_cur[128];
    int b = blockIdx.x;
    int tid = threadIdx.x;
    int n0 = b * 128;
    int nb = min(128, NN - n0);
    int est = bucketEdgeStart[b];
    int ecnt = min(bucketCnt[b], BCAP);
    if (tid < 128) s_cnt[tid] = 0;
    __syncthreads();
    for (int i = tid; i < ecnt; i += 256) {
        unsigned v = ebuf[est + i];
        s_e[i] = v;
        atomicAdd(&s_cnt[v & 127u], 1);
    }
    __syncthreads();
    int myc = 0;
    if (tid < 128) {
        myc = (tid < nb) ? s_cnt[tid] + 1 : 0;   // +1 self-loop
        s_scan[tid] = myc;
    }
    __syncthreads();
    for (int off = 1; off < 128; off <<= 1) {
        int a = 0;
        if (tid < 128 && tid >= off) a = s_scan[tid - off];
        __syncthreads();
        if (tid < 128) s_scan[tid] += a;
        __syncthreads();
    }
    if (tid < nb) {
        int slotbase = bucketSlotStart[b] + s_scan[tid] - myc;
        col_start[n0 + tid] = slotbase;
        dinv[n0 + tid] = rsqrtf((float)(s_cnt[tid] + 1));
        srcv[slotbase] = n0 + tid;               // self-loop first
        s_cur[tid] = slotbase + 1;
    }
    __syncthreads();
    for (int i = tid; i < ecnt; i += 256) {
        unsigned v = s_e[i];
        int slot = atomicAdd(&s_cur[v & 127u], 1);
        srcv[slot] = (int)(v >> 7);
    }
}

// batch is sorted -> group bounds are run boundaries; plain stores, no atomics.
__global__ void bounds_kernel(const int* __restrict__ batch, int* gstart, int* gend) {
    int i = blockIdx.x * blockDim.x + threadIdx.x;
    if (i >= NN) return;
    int b = batch[i];
    if (i == 0) {
        gstart[b] = 0;
    } else {
        int bp = batch[i - 1];
        if (b != bp) {
            gstart[b] = i;
            gend[bp] = i;
        }
    }
    if (i == NN - 1) gend[b] = NN;
}

// cast+transpose all 3 W (fp32 [k][n]) -> Wt bf16 [n][k], one launch
__global__ void wprep_kernel(const float* __restrict__ W0, const float* __restrict__ W1,
                             const float* __restrict__ W2, unsigned short* __restrict__ Wt) {
    int i = blockIdx.x * 256 + threadIdx.x;
    int l = i >> 14;                      // HH*HH = 16384 per layer
    int r = i & 16383;
    if (l < 3) {
        const float* W = (l == 0) ? W0 : (l == 1) ? W1 : W2;
        int k = r >> 7, n = r & 127;
        Wt[l * HH * HH + n * HH + k] = f2bf(W[r]);
    }
}

// cast x fp32 -> Xbf (packed 2 bf16 per uint; low = even col)
__global__ void cast_kernel(const float* __restrict__ x, unsigned* __restrict__ Xbf) {
    int i = blockIdx.x * blockDim.x + threadIdx.x;   // uint index
    if (i >= NN * 64) return;
    float2 v = ((const float2*)x)[i];
    Xbf[i] = (unsigned)f2bf(v.x) | ((unsigned)f2bf(v.y) << 16);
}

// ---------------- per-layer kernels ----------------

// one wave per dst node; uint4 gathers (16B/lane, 4 rows/issue, 4-pair unroll = 16 rows
// in flight); cross-quarter shfl reduce; bf16 out. Block 0 zeroes BN stats.
__global__ __launch_bounds__(256) void agg_kernel(const uint4* __restrict__ Xbf4,
                                                  const int* __restrict__ col_start,
                                                  const int* __restrict__ srcv,
                                                  const float* __restrict__ dinv,
                                                  unsigned short* __restrict__ Abf,
                                                  float* __restrict__ gsum,
                                                  float* __restrict__ gsq) {
    if (blockIdx.x == 0 && threadIdx.x < HH) {
        gsum[threadIdx.x] = 0.f;
        gsq[threadIdx.x] = 0.f;
    }
    int wid = (int)((blockIdx.x * blockDim.x + threadIdx.x) >> 6);
    int lane = threadIdx.x & 63;
    if (wid >= NN) return;
    int s0 = col_start[wid], s1 = col_start[wid + 1];
    float dd = dinv[wid];
    int q = lane >> 4;        // quarter: which neighbor of the group of 4
    int l16 = lane & 15;      // 16 lanes cover one 256B row (uint4 each)
    float acc[8];
#pragma unroll
    for (int j = 0; j < 8; ++j) acc[j] = 0.f;

    for (int base = s0; base < s1; base += 64) {
        int cnt = min(64, s1 - base);
        int msrc = 0;
        float mw = 0.f;
        if (lane < cnt) { msrc = srcv[base + lane]; mw = dinv[msrc] * dd; }
        int rounds = (cnt + 3) >> 2;
        int p = 0;
        for (; p + 4 <= rounds; p += 4) {
            uint4 u[4];
            float w[4];
#pragma unroll
            for (int k = 0; k < 4; ++k) {
                int idx = (p + k) * 4 + q;
                int src = __shfl(msrc, idx);
                w[k] = __shfl(mw, idx);           // 0 beyond cnt
                u[k] = Xbf4[(size_t)src * 16 + l16];
            }
#pragma unroll
            for (int k = 0; k < 4; ++k) {
                acc[0] += w[k] * __uint_as_float(u[k].x << 16);
                acc[1] += w[k] * __uint_as_float(u[k].x & 0xFFFF0000u);
                acc[2] += w[k] * __uint_as_float(u[k].y << 16);
                acc[3] += w[k] * __uint_as_float(u[k].y & 0xFFFF0000u);
                acc[4] += w[k] * __uint_as_float(u[k].z << 16);
                acc[5] += w[k] * __uint_as_float(u[k].z & 0xFFFF0000u);
                acc[6] += w[k] * __uint_as_float(u[k].w << 16);
                acc[7] += w[k] * __uint_as_float(u[k].w & 0xFFFF0000u);
            }
        }
        for (; p < rounds; ++p) {
            int idx = p * 4 + q;
            int src = __shfl(msrc, idx);
            float w = __shfl(mw, idx);
            uint4 u = Xbf4[(size_t)src * 16 + l16];
            acc[0] += w * __uint_as_float(u.x << 16);
            acc[1] += w * __uint_as_float(u.x & 0xFFFF0000u);
            acc[2] += w * __uint_as_float(u.y << 16);
            acc[3] += w * __uint_as_float(u.y & 0xFFFF0000u);
            acc[4] += w * __uint_as_float(u.z << 16);
            acc[5] += w * __uint_as_float(u.z & 0xFFFF0000u);
            acc[6] += w * __uint_as_float(u.w << 16);
            acc[7] += w * __uint_as_float(u.w & 0xFFFF0000u);
        }
    }
#pragma unroll
    for (int j = 0; j < 8; ++j) {
        acc[j] += __shfl_xor(acc[j], 16);
        acc[j] += __shfl_xor(acc[j], 32);
    }
    if (q == 0) {
        uint4 pk;
        pk.x = (unsigned)f2bf(acc[0]) | ((unsigned)f2bf(acc[1]) << 16);
        pk.y = (unsigned)f2bf(acc[2]) | ((unsigned)f2bf(acc[3]) << 16);
        pk.z = (unsigned)f2bf(acc[4]) | ((unsigned)f2bf(acc[5]) << 16);
        pk.w = (unsigned)f2bf(acc[6]) | ((unsigned)f2bf(acc[7]) << 16);
        ((uint4*)Abf)[(size_t)wid * 16 + l16] = pk;
    }
}

// pass 1: MFMA product, BN column sum/sumsq only — H never materialized.
__global__ __launch_bounds__(256) void gemm_stats_kernel(const unsigned short* __restrict__ Abf,
                                                         const unsigned short* __restrict__ Wt,
                                                         const float* __restrict__ bias,
                                                         float* __restrict__ gsum,
                                                         float* __restrict__ gsq) {
    __shared__ unsigned short wlds[128 * 136];   // row stride 136 bf16 = 272B: no b128 conflicts
    __shared__ float ssum[HH], ssq[HH];
    int tid = threadIdx.x;
    if (tid < HH) { ssum[tid] = 0.f; ssq[tid] = 0.f; }
#pragma unroll
    for (int it = 0; it < 16; ++it) {
        int idx = it * 256 + tid;
        int r = idx >> 5, c = idx & 31;
        *(uint2*)&wlds[r * 136 + c * 4] = *(const uint2*)(Wt + r * HH + c * 4);
    }
    __syncthreads();

    int lane = tid & 63;
    int wave = tid >> 6;
    int mcol = lane & 15;
    int quad = lane >> 4;
    int rowbase = blockIdx.x * 128 + wave * 32;
    int row0 = rowbase + mcol;
    int row1 = row0 + 16;

    f32x4 acc[2][8];
#pragma unroll
    for (int mt = 0; mt < 2; ++mt)
#pragma unroll
        for (int nt = 0; nt < 8; ++nt) acc[mt][nt] = (f32x4){0.f, 0.f, 0.f, 0.f};

    s16x8 zf = {0, 0, 0, 0, 0, 0, 0, 0};
#pragma unroll
    for (int ks = 0; ks < 4; ++ks) {
        int k0 = ks * 32 + quad * 8;
        s16x8 a0 = (row0 < NN) ? *(const s16x8*)(Abf + (size_t)row0 * HH + k0) : zf;
        s16x8 a1 = (row1 < NN) ? *(const s16x8*)(Abf + (size_t)row1 * HH + k0) : zf;
#pragma unroll
        for (int nt = 0; nt < 8; ++nt) {
            s16x8 b = *(const s16x8*)&wlds[(nt * 16 + mcol) * 136 + k0];
            acc[0][nt] = __builtin_amdgcn_mfma_f32_16x16x32_bf16(a0, b, acc[0][nt], 0, 0, 0);
            acc[1][nt] = __builtin_amdgcn_mfma_f32_16x16x32_bf16(a1, b, acc[1][nt], 0, 0, 0);
        }
    }

    float s[8], sq[8];
#pragma unroll
    for (int nt = 0; nt < 8; ++nt) { s[nt] = 0.f; sq[nt] = 0.f; }
#pragma unroll
    for (int mt = 0; mt < 2; ++mt) {
        int rbase = rowbase + mt * 16 + quad * 4;
#pragma unroll
        for (int nt = 0; nt < 8; ++nt) {
            float bv = bias[nt * 16 + mcol];
            f32x4 a = acc[mt][nt];
#pragma unroll
            for (int reg = 0; reg < 4; ++reg) {
                if (rbase + reg < NN) {
                    float h = a[reg] + bv;
                    s[nt] += h; sq[nt] += h * h;
                }
            }
        }
    }
#pragma unroll
    for (int nt = 0; nt < 8; ++nt) {
        float v = s[nt];  v += __shfl_xor(v, 16);  v += __shfl_xor(v, 32);
        float w = sq[nt]; w += __shfl_xor(w, 16);  w += __shfl_xor(w, 32);
        if (quad == 0) {
            atomicAdd(&ssum[nt * 16 + mcol], v);
            atomicAdd(&ssq[nt * 16 + mcol], w);
        }
    }
    __syncthreads();
    if (tid < HH) {
        atomicAdd(&gsum[tid], ssum[tid]);
        atomicAdd(&gsq[tid], ssq[tid]);
    }
}

// pass 2: recompute the identical MFMA product, apply bias+BN+ReLU, store bf16 X.
__global__ __launch_bounds__(256) void gemm_apply_kernel(const unsigned short* __restrict__ Abf,
                                                         const unsigned short* __restrict__ Wt,
                                                         const float* __restrict__ bias,
                                                         const float* __restrict__ gsum,
                                                         const float* __restrict__ gsq,
                                                         const float* __restrict__ g,
                                                         const float* __restrict__ beta,
                                                         unsigned short* __restrict__ Xb16) {
    __shared__ unsigned short wlds[128 * 136];
    __shared__ float asc[HH], bsh[HH];
    int tid = threadIdx.x;
#pragma unroll
    for (int it = 0; it < 16; ++it) {
        int idx = it * 256 + tid;
        int r = idx >> 5, c = idx & 31;
        *(uint2*)&wlds[r * 136 + c * 4] = *(const uint2*)(Wt + r * HH + c * 4);
    }
    if (tid < HH) {
        float mu = gsum[tid] * (1.f / (float)NN);
        float var = fmaxf(gsq[tid] * (1.f / (float)NN) - mu * mu, 0.f);
        float a = g[tid] * rsqrtf(var + 1e-5f);
        asc[tid] = a;
        bsh[tid] = a * (bias[tid] - mu) + beta[tid];   // o = a*acc + bsh
    }
    __syncthreads();

    int lane = tid & 63;
    int wave = tid >> 6;
    int mcol = lane & 15;
    int quad = lane >> 4;
    int rowbase = blockIdx.x * 128 + wave * 32;
    int row0 = rowbase + mcol;
    int row1 = row0 + 16;

    f32x4 acc[2][8];
#pragma unroll
    for (int mt = 0; mt < 2; ++mt)
#pragma unroll
        for (int nt = 0; nt < 8; ++nt) acc[mt][nt] = (f32x4){0.f, 0.f, 0.f, 0.f};

    s16x8 zf = {0, 0, 0, 0, 0, 0, 0, 0};
#pragma unroll
    for (int ks = 0; ks < 4; ++ks) {
        int k0 = ks * 32 + quad * 8;
        s16x8 a0 = (row0 < NN) ? *(const s16x8*)(Abf + (size_t)row0 * HH + k0) : zf;
        s16x8 a1 = (row1 < NN) ? *(const s16x8*)(Abf + (size_t)row1 * HH + k0) : zf;
#pragma unroll
        for (int nt = 0; nt < 8; ++nt) {
            s16x8 b = *(const s16x8*)&wlds[(nt * 16 + mcol) * 136 + k0];
            acc[0][nt] = __builtin_amdgcn_mfma_f32_16x16x32_bf16(a0, b, acc[0][nt], 0, 0, 0);
            acc[1][nt] = __builtin_amdgcn_mfma_f32_16x16x32_bf16(a1, b, acc[1][nt], 0, 0, 0);
        }
    }

#pragma unroll
    for (int mt = 0; mt < 2; ++mt) {
        int rbase = rowbase + mt * 16 + quad * 4;
#pragma unroll
        for (int nt = 0; nt < 8; ++nt) {
            int col = nt * 16 + mcol;
            float av = asc[col], bv = bsh[col];
            f32x4 a = acc[mt][nt];
#pragma unroll
            for (int reg = 0; reg < 4; ++reg) {
                int r = rbase + reg;
                if (r < NN) {
                    float o = fmaxf(av * a[reg] + bv, 0.f);
                    Xb16[(size_t)r * HH + col] = f2bf(o);
                }
            }
        }
    }
}

// ---------------- pooling + fc ----------------

__global__ void pool_kernel(const unsigned* __restrict__ Xbf, const int* __restrict__ gstart,
                            const int* __restrict__ gend, float* __restrict__ poolsum) {
    int g = blockIdx.x;
    int sp = blockIdx.y;
    int t = threadIdx.x;           // 64: each handles 2 cols
    int s = gstart[g], e = gend[g];
    if (e <= s) return;
    int len = e - s;
    int chunk = (len + PSPLIT - 1) / PSPLIT;
    int cs = s + sp * chunk;
    int ce = min(cs + chunk, e);
    if (cs >= ce) return;
    float2 acc = make_float2(0.f, 0.f);
    for (int i = cs; i < ce; ++i) {
        unsigned u = Xbf[(size_t)i * 64 + t];
        acc.x += __uint_as_float(u << 16);
        acc.y += __uint_as_float(u & 0xFFFF0000u);
    }
    atomicAdd(&poolsum[g * HH + 2 * t], acc.x);
    atomicAdd(&poolsum[g * HH + 2 * t + 1], acc.y);
}

__global__ void fc_kernel(const float* __restrict__ poolsum, const int* __restrict__ gstart,
                          const int* __restrict__ gend, const float* __restrict__ fc_w,
                          const float* __restrict__ fc_b, float* __restrict__ out) {
    int g = blockIdx.x;
    int o = threadIdx.x;
    int cnt = gend[g] - gstart[g];
    float inv = (cnt > 0) ? (1.f / (float)cnt) : 0.f;
    float acc = fc_b[o];
    for (int k = 0; k < HH; ++k) acc += (poolsum[g * HH + k] * inv) * fc_w[k * HH + o];
    out[g * HH + o] = acc;
}

// ---------------- launch ----------------

extern "C" void kernel_launch(void* const* d_in, const int* in_sizes, int n_in,
                              void* d_out, int out_size, void* d_ws, size_t ws_size,
                              hipStream_t stream) {
    const float* x     = (const float*)d_in[0];
    const int*   ei    = (const int*)d_in[1];
    const int*   batch = (const int*)d_in[2];
    const float* Wl[3]    = {(const float*)d_in[3], (const float*)d_in[7], (const float*)d_in[11]};
    const float* bl[3]    = {(const float*)d_in[4], (const float*)d_in[8], (const float*)d_in[12]};
    const float* gl[3]    = {(const float*)d_in[5], (const float*)d_in[9], (const float*)d_in[13]};
    const float* betal[3] = {(const float*)d_in[6], (const float*)d_in[10], (const float*)d_in[14]};
    const float* fc_w = (const float*)d_in[15];
    const float* fc_b = (const float*)d_in[16];
    float* out = (float*)d_out;

    char* ws = (char*)d_ws;
    size_t off = 0;
    auto take = [&](size_t n) -> void* {
        void* p = ws + off;
        off = (off + n + 255) & ~(size_t)255;
        return p;
    };
    int*   bucketCnt       = (int*)take((size_t)NB * 4);
    int*   bucketEdgeStart = (int*)take((size_t)NB * 4);
    int*   bucketSlotStart = (int*)take((size_t)NB * 4);
    int*   cursor          = (int*)take((size_t)NB * 4);
    unsigned* ebuf         = (unsigned*)take((size_t)EE * 4);
    int*   col_start       = (int*)take((size_t)(NN + 1) * 4);
    float* dinv            = (float*)take((size_t)NN * 4);
    int*   srcv            = (int*)take((size_t)TOT * 4);
    float* gsum            = (float*)take(HH * 4);
    float* gsq             = (float*)take(HH * 4);
    int*   gstart          = (int*)take(GG * 4);
    int*   gend            = (int*)take(GG * 4);
    float* poolsum         = (float*)take((size_t)GG * HH * 4);
    unsigned short* wt     = (unsigned short*)take((size_t)3 * HH * HH * 2);
    unsigned* Xbf          = (unsigned*)take((size_t)NN * 64 * 4);
    unsigned short* Abf    = (unsigned short*)take((size_t)NN * HH * 2);

    init_kernel<<<(NN + 255) / 256, 256, 0, stream>>>(bucketCnt, gstart, gend, poolsum);
    hist_kernel<<<512, 256, 0, stream>>>(ei, bucketCnt);
    bscan_kernel<<<1, 1024, 0, stream>>>(bucketCnt, bucketEdgeStart, bucketSlotStart, cursor, col_start);
    bfill2_kernel<<<(EE + FCHUNK - 1) / FCHUNK, 256, 0, stream>>>(ei, cursor, ebuf);
    bproc_kernel<<<NB, 256, 0, stream>>>(ebuf, bucketCnt, bucketEdgeStart, bucketSlotStart,
                                         col_start, dinv, srcv);
    bounds_kernel<<<(NN + 255) / 256, 256, 0, stream>>>(batch, gstart, gend);
    wprep_kernel<<<(3 * HH * HH + 255) / 256, 256, 0, stream>>>(Wl[0], Wl[1], Wl[2], wt);
    cast_kernel<<<(NN * 64 + 255) / 256, 256, 0, stream>>>(x, Xbf);

    for (int l = 0; l < 3; ++l) {
        const unsigned short* W = wt + (size_t)l * HH * HH;
        agg_kernel<<<(NN * 64 + 255) / 256, 256, 0, stream>>>((const uint4*)Xbf, col_start, srcv,
                                                              dinv, Abf, gsum, gsq);
        gemm_stats_kernel<<<(NN + 127) / 128, 256, 0, stream>>>(Abf, W, bl[l], gsum, gsq);
        gemm_apply_kernel<<<(NN + 127) / 128, 256, 0, stream>>>(Abf, W, bl[l], gsum, gsq,
                                                                gl[l], betal[l],
                                                                (unsigned short*)Xbf);
    }

    pool_kernel<<<dim3(GG, PSPLIT), 64, 0, stream>>>(Xbf, gstart, gend, poolsum);
    fc_kernel<<<GG, 128, 0, stream>>>(poolsum, gstart, gend, fc_w, fc_b, out);
}